// Round 1
// baseline (126.333 us; speedup 1.0000x reference)
//
#include <hip/hip_runtime.h>

// IDCT (DCT-III) of 4096 rows x 4096 cols via per-row 4096-point complex FFT
// (Makhoul single-FFT formulation):
//   a_n = w_n * x_n * exp(+j*pi*n/(2N)),  w_0=1, w_n=2
//   u_m = sum_n a_n exp(+j*2*pi*n*m/N)      (N-point, sign +1, unnormalized)
//   y[2m] = Re u[m],  y[2m+1] = Re u[N-1-m],  m = 0..N/2-1
//
// One workgroup (256 threads) per row. Radix-16, 3 stages (16^3 = 4096),
// Stockham ordering (natural-order output), in-place LDS with read/barrier/write.
// Twiddle quarter table comes EXACTLY from expk: expk[4r] = (cos(2*pi*r/N), -sin(...)).

#define NFFT 4096
#define NT   256
#define PADIDX(i) ((i) + ((i) >> 4))     // +1 float pad per 16 -> breaks power-of-2 bank strides
#define PADN  (NFFT + (NFFT >> 4))       // 4352

__device__ __forceinline__ void cmul(float ar, float ai, float br, float bi,
                                     float& orr, float& oii) {
    orr = ar * br - ai * bi;
    oii = ar * bi + ai * br;
}

// 16-point DFT, sign +1 (inverse direction), natural order, in place.
// Implemented as two internal radix-4 Stockham stages; W16[p][r] = exp(+i*2pi*p*r/16).
__device__ __forceinline__ void dft16(float vr[16], float vi[16]) {
    constexpr float WR[4][4] = {
        {1.f, 1.f, 1.f, 1.f},
        {1.f,  0.92387953251128674f,  0.70710678118654752f,  0.38268343236508977f},
        {1.f,  0.70710678118654752f,  0.f,                  -0.70710678118654752f},
        {1.f,  0.38268343236508977f, -0.70710678118654752f, -0.92387953251128674f}};
    constexpr float WI[4][4] = {
        {0.f, 0.f, 0.f, 0.f},
        {0.f,  0.38268343236508977f,  0.70710678118654752f,  0.92387953251128674f},
        {0.f,  0.70710678118654752f,  1.f,                   0.70710678118654752f},
        {0.f,  0.92387953251128674f,  0.70710678118654752f, -0.38268343236508977f}};
    float ur[16], ui[16];
#pragma unroll
    for (int p = 0; p < 4; ++p) {
        float apcr = vr[p] + vr[p + 8],      apci = vi[p] + vi[p + 8];
        float amcr = vr[p] - vr[p + 8],      amci = vi[p] - vi[p + 8];
        float bpdr = vr[p + 4] + vr[p + 12], bpdi = vi[p + 4] + vi[p + 12];
        float bmdr = vr[p + 4] - vr[p + 12], bmdi = vi[p + 4] - vi[p + 12];
        // Y0..Y3 of radix-4 with omega_4 = +i
        float y0r = apcr + bpdr, y0i = apci + bpdi;
        float y1r = amcr - bmdi, y1i = amci + bmdr;   // amc + i*bmd
        float y2r = apcr - bpdr, y2i = apci - bpdi;
        float y3r = amcr + bmdi, y3i = amci - bmdr;   // amc - i*bmd
        ur[4 * p + 0] = y0r;  ui[4 * p + 0] = y0i;
        cmul(y1r, y1i, WR[p][1], WI[p][1], ur[4 * p + 1], ui[4 * p + 1]);
        cmul(y2r, y2i, WR[p][2], WI[p][2], ur[4 * p + 2], ui[4 * p + 2]);
        cmul(y3r, y3i, WR[p][3], WI[p][3], ur[4 * p + 3], ui[4 * p + 3]);
    }
#pragma unroll
    for (int q = 0; q < 4; ++q) {
        float apcr = ur[q] + ur[q + 8],      apci = ui[q] + ui[q + 8];
        float amcr = ur[q] - ur[q + 8],      amci = ui[q] - ui[q + 8];
        float bpdr = ur[q + 4] + ur[q + 12], bpdi = ui[q + 4] + ui[q + 12];
        float bmdr = ur[q + 4] - ur[q + 12], bmdi = ui[q + 4] - ui[q + 12];
        vr[q]      = apcr + bpdr;  vi[q]      = apci + bpdi;
        vr[q + 4]  = amcr - bmdi;  vi[q + 4]  = amci + bmdr;
        vr[q + 8]  = apcr - bpdr;  vi[q + 8]  = apci - bpdi;
        vr[q + 12] = amcr + bmdi;  vi[q + 12] = amci - bmdr;
    }
}

// v[r] *= w1^r, r=1..15 (sequential power chain; rel err ~15 ulp, fine for fp32 FFT)
__device__ __forceinline__ void twiddle_apply(float vr[16], float vi[16],
                                              float w1r, float w1i) {
    float cr = w1r, ci = w1i;
#pragma unroll
    for (int r = 1; r < 16; ++r) {
        float tr, ti;
        cmul(vr[r], vi[r], cr, ci, tr, ti);
        vr[r] = tr; vi[r] = ti;
        if (r < 15) {
            float nr, ni;
            cmul(cr, ci, w1r, w1i, nr, ni);
            cr = nr; ci = ni;
        }
    }
}

extern "C" __global__ void __launch_bounds__(NT, 3)
idct_fft_kernel(const float* __restrict__ x, const float* __restrict__ expk,
                float* __restrict__ out)
{
    __shared__ float Sr[PADN], Si[PADN];
    __shared__ float Twr[NFFT / 4], Twi[NFFT / 4];

    const int tid = threadIdx.x;
    const long row = blockIdx.x;
    const float* __restrict__ xrow = x + row * (long)NFFT;
    const float2* __restrict__ e2 = (const float2*)expk;

    // Quarter-wave twiddle table (exact, from input): Tw[r] = exp(+i*2pi*r/N)
#pragma unroll
    for (int j = 0; j < 4; ++j) {
        int r = tid + NT * j;
        float2 e = e2[4 * r];
        Twr[r] = e.x;
        Twi[r] = -e.y;
    }

    // ---- stage 1 (s = 1): fused global load + premultiply ----
    float vr[16], vi[16];
#pragma unroll
    for (int j = 0; j < 16; ++j) {
        int n = tid + NT * j;
        float xv = xrow[n];
        float2 e = e2[n];                       // (cos t, -sin t), t = pi*n/(2N)
        float w = (n == 0) ? 1.0f : 2.0f;
        vr[j] = w * xv * e.x;                   // w*x*cos
        vi[j] = -(w * xv * e.y);                // w*x*sin
    }
    __syncthreads();                            // twiddle table ready
    dft16(vr, vi);
    twiddle_apply(vr, vi, Twr[tid], Twi[tid]);  // exponent s*p = tid
#pragma unroll
    for (int r = 0; r < 16; ++r) {
        int a = PADIDX(16 * tid + r);
        Sr[a] = vr[r]; Si[a] = vi[r];
    }
    __syncthreads();

    // ---- stage 2 (s = 16) ----
#pragma unroll
    for (int j = 0; j < 16; ++j) {
        int a = PADIDX(tid + NT * j);
        vr[j] = Sr[a]; vi[j] = Si[a];
    }
    __syncthreads();                            // all reads done before in-place writes
    dft16(vr, vi);
    {
        int e = tid & ~15;                      // exponent s*p = 16*(tid>>4)
        twiddle_apply(vr, vi, Twr[e], Twi[e]);
    }
    {
        int ba = (tid & 15) + 16 * (tid & ~15); // q + 256*p
#pragma unroll
        for (int r = 0; r < 16; ++r) {
            int a = PADIDX(ba + 16 * r);
            Sr[a] = vr[r]; Si[a] = vi[r];
        }
    }
    __syncthreads();

    // ---- stage 3 (s = 256): twiddles unity; only real part needed downstream ----
#pragma unroll
    for (int j = 0; j < 16; ++j) {
        int a = PADIDX(tid + NT * j);
        vr[j] = Sr[a]; vi[j] = Si[a];
    }
    __syncthreads();
    dft16(vr, vi);
#pragma unroll
    for (int r = 0; r < 16; ++r) {
        Sr[PADIDX(tid + NT * r)] = vr[r];       // store Re(u) at natural index
    }
    __syncthreads();

    // ---- output: y[2m] = Re u[m], y[2m+1] = Re u[N-1-m] ----
    float2* __restrict__ y2 = (float2*)(out + row * (long)NFFT);
#pragma unroll
    for (int t = 0; t < 8; ++t) {
        int m = tid + NT * t;
        float a = Sr[PADIDX(m)];
        float b = Sr[PADIDX(NFFT - 1 - m)];
        y2[m] = make_float2(a, b);              // coalesced 8B/lane stores
    }
}

extern "C" void kernel_launch(void* const* d_in, const int* in_sizes, int n_in,
                              void* d_out, int out_size, void* d_ws, size_t ws_size,
                              hipStream_t stream) {
    const float* x    = (const float*)d_in[0];
    const float* expk = (const float*)d_in[1];
    float* out        = (float*)d_out;
    const int nrows   = in_sizes[0] / NFFT;     // 4096 rows
    hipLaunchKernelGGL(idct_fft_kernel, dim3(nrows), dim3(NT), 0, stream,
                       x, expk, out);
}